// Round 1
// baseline (346.464 us; speedup 1.0000x reference)
//
#include <hip/hip_runtime.h>
#include <cmath>

// Shapes: B=4, V=8, D=64, N=16, H=32, W=32, GROUPS=4
// rotation tables: a = radians(-45*v); c = cos(a), s = sin(a)
#define FSQ 0.70710678118654752440f
__constant__ float CTAB[8] = {1.f,  FSQ, 0.f, -FSQ, -1.f, -FSQ, 0.f, FSQ};
__constant__ float STAB[8] = {0.f, -FSQ, -1.f, -FSQ,  0.f,  FSQ, 1.f, FSQ};

// ---------------------------------------------------------------------------
// GroupNorm: 16 blocks = (b, group). Writes u_norm into zero-padded (34x34)
// planes in ws (border zeros == conv SAME padding).
// ---------------------------------------------------------------------------
__global__ __launch_bounds__(256) void gn_kernel(const float* __restrict__ u,
                                                 const float* __restrict__ gw,
                                                 const float* __restrict__ gb,
                                                 float* __restrict__ up)
{
    int blk = blockIdx.x;            // b*4 + g
    int b = blk >> 2, g = blk & 3;
    int t = threadIdx.x;
    const float* src = u + ((size_t)(b * 64 + g * 16) << 10);   // 16384 floats
    float sum = 0.f, sq = 0.f;
    #pragma unroll
    for (int r = 0; r < 64; ++r) {
        float v = src[t + (r << 8)];
        sum += v; sq += v * v;
    }
    __shared__ float red[256], red2[256];
    red[t] = sum; red2[t] = sq;
    __syncthreads();
    for (int ofs = 128; ofs > 0; ofs >>= 1) {
        if (t < ofs) { red[t] += red[t + ofs]; red2[t] += red2[t + ofs]; }
        __syncthreads();
    }
    float mu  = red[0] * (1.f / 16384.f);
    float var = red2[0] * (1.f / 16384.f) - mu * mu;
    float rs  = rsqrtf(var + 1e-5f);

    float* pb = up + (size_t)(b * 64 + g * 16) * 1156;
    // zero the 132 border cells of each of my 16 padded planes
    for (int k = t; k < 16 * 132; k += 256) {
        int pl = k / 132, c = k % 132;
        int idx;
        if (c < 34)       idx = c;                       // row 0
        else if (c < 68)  idx = 33 * 34 + (c - 34);      // row 33
        else if (c < 100) idx = (c - 68 + 1) * 34;       // col 0, rows 1..32
        else              idx = (c - 100 + 1) * 34 + 33; // col 33, rows 1..32
        pb[pl * 1156 + idx] = 0.f;
    }
    // normalized data cells
    for (int r = 0; r < 64; ++r) {
        int idx = t + (r << 8);
        int ch = idx >> 10, rem = idx & 1023;
        int y = rem >> 5, x = rem & 31;
        float val = (src[idx] - mu) * rs * gw[g * 16 + ch] + gb[g * 16 + ch];
        pb[ch * 1156 + (y + 1) * 34 + (x + 1)] = val;
    }
}

// ---------------------------------------------------------------------------
// 3x3 SAME convs over u_norm: 96 output channels (64 delta + 16 B + 16 C).
// 384 blocks = (b, o). Thread owns 4 vertically-adjacent pixels:
// 18 tap loads -> 36 FMAs per input channel. Delta epilogue: softplus+clip.
// ---------------------------------------------------------------------------
__global__ __launch_bounds__(256) void conv_kernel(const float* __restrict__ up,
                                                   const float* __restrict__ wd,
                                                   const float* __restrict__ bd,
                                                   const float* __restrict__ wB,
                                                   const float* __restrict__ wC,
                                                   const float* __restrict__ dtb,
                                                   float* __restrict__ delta,
                                                   float* __restrict__ Bv,
                                                   float* __restrict__ Cv)
{
    int blk = blockIdx.x;
    int o = blk % 96, b = blk / 96;
    int t = threadIdx.x;
    int w = t & 31, h0 = (t >> 5) << 2;   // 4 rows h0..h0+3, column w
    const float* wsel;
    if (o < 64)      wsel = wd + (size_t)o * 576;
    else if (o < 80) wsel = wB + (size_t)(o - 64) * 576;
    else             wsel = wC + (size_t)(o - 80) * 576;
    const float* plane = up + (size_t)b * 64 * 1156;

    float acc[4] = {0.f, 0.f, 0.f, 0.f};
    for (int ci = 0; ci < 64; ++ci) {
        const float* pl = plane + ci * 1156 + h0 * 34 + w;
        const float* wp = wsel + ci * 9;
        float v[6][3];
        #pragma unroll
        for (int ry = 0; ry < 6; ++ry)
            #pragma unroll
            for (int dx = 0; dx < 3; ++dx)
                v[ry][dx] = pl[ry * 34 + dx];
        float w9[9];
        #pragma unroll
        for (int k = 0; k < 9; ++k) w9[k] = wp[k];
        #pragma unroll
        for (int r = 0; r < 4; ++r)
            #pragma unroll
            for (int dy = 0; dy < 3; ++dy)
                #pragma unroll
                for (int dx = 0; dx < 3; ++dx)
                    acc[r] += v[r + dy][dx] * w9[dy * 3 + dx];
    }

    int pbase = (h0 << 5) + w;
    if (o < 64) {
        float bias = bd[o] + dtb[0];
        float* dst = delta + ((size_t)(b * 64 + o) << 10) + pbase;
        #pragma unroll
        for (int r = 0; r < 4; ++r) {
            float x = acc[r] + bias;
            float sp = (x > 20.f) ? x : log1pf(expf(x));
            sp = fminf(fmaxf(sp, 1e-4f), 5.f);
            dst[r << 5] = sp;
        }
    } else {
        float* dst = (o < 80) ? (Bv + ((size_t)(b * 16 + o - 64) << 10) + pbase)
                              : (Cv + ((size_t)(b * 16 + o - 80) << 10) + pbase);
        #pragma unroll
        for (int r = 0; r < 4; ++r) dst[r << 5] = acc[r];
    }
}

// ---------------------------------------------------------------------------
// Main fused kernel: 2048 blocks = (b, v, d). Stages s_prev[b,v,d] in two
// 8-plane chunks into LDS (row stride 33 + zeroed guard halo), computes
// bilinear transport + state update, streams s_new out, reduces y over n.
// LDS plane layout: idx = 34 + n*1056 + y*33 + x  (y,x in 0..31).
// Guard: [0..33] front, col-32 pads, [8482..8515] tail — all zeroed once.
// ---------------------------------------------------------------------------
__global__ __launch_bounds__(256) void fused_state_kernel(
    const float* __restrict__ s_prev, const float* __restrict__ u_t,
    const float* __restrict__ delta, const float* __restrict__ Bv,
    const float* __restrict__ Cv, const float* __restrict__ logA,
    const float* __restrict__ Dp, float* __restrict__ y_out,
    float* __restrict__ s_out)
{
    __shared__ float lds[8516];
    __shared__ float Ash[16];
    int blk = blockIdx.x;
    int d = blk & 63, v = (blk >> 6) & 7, b = blk >> 9;
    int t = threadIdx.x;

    if (t < 16) Ash[t] = -expf(logA[d * 16 + t]);
    // zero guard cells (324 of them)
    for (int k = t; k < 324; k += 256) {
        int idx;
        if (k < 34)       idx = k;
        else if (k < 290) { int q = k - 34; idx = 34 + (q >> 5) * 1056 + (q & 31) * 33 + 32; }
        else              idx = 8482 + (k - 290);
        lds[idx] = 0.f;
    }

    const float cc = CTAB[v], ss = STAB[v];
    const float* dpl = delta + ((size_t)(b * 64 + d) << 10);
    const float* upl = u_t   + ((size_t)(b * 64 + d) << 10);

    float w00[4], w01[4], w10[4], w11[4], du[4], dl[4], uu[4], yacc[4];
    int base[4];
    #pragma unroll
    for (int i = 0; i < 4; ++i) {
        int p = t + (i << 8);
        int h = p >> 5, wpx = p & 31;
        float X = (wpx + 0.5f) * 0.0625f - 1.f;
        float Y = (h + 0.5f) * 0.0625f - 1.f;
        float gx = cc * X - ss * Y;
        float gy = ss * X + cc * Y;
        float ix = (gx + 1.f) * 16.f - 0.5f;
        float iy = (gy + 1.f) * 16.f - 0.5f;
        float fx0 = floorf(ix), fy0 = floorf(iy);
        float wx = ix - fx0, wy = iy - fy0;
        int x0 = (int)fx0, y0 = (int)fy0;
        bool vx0 = (x0 >= 0) && (x0 < 32);
        bool vx1 = (x0 >= -1) && (x0 < 31);
        bool vy0 = (y0 >= 0) && (y0 < 32);
        bool vy1 = (y0 >= -1) && (y0 < 31);
        float mx0 = vx0 ? (1.f - wx) : 0.f;
        float mx1 = vx1 ? wx : 0.f;
        float my0 = vy0 ? (1.f - wy) : 0.f;
        float my1 = vy1 ? wy : 0.f;
        w00[i] = my0 * mx0; w01[i] = my0 * mx1;
        w10[i] = my1 * mx0; w11[i] = my1 * mx1;
        int bx = min(max(x0, -1), 31), by = min(max(y0, -1), 31);
        base[i] = 34 + by * 33 + bx;   // taps: +0, +1, +33, +34 (invalid taps land on zeroed guard)
        float dd = dpl[p], uv = upl[p];
        dl[i] = dd; uu[i] = uv; du[i] = dd * uv; yacc[i] = 0.f;
    }

    size_t so = ((size_t)((b * 8 + v) * 64 + d)) << 14;   // *16384
    const float* sb  = s_prev + so;
    float* sob = s_out + so;
    const float* BvB = Bv + ((size_t)b << 14);
    const float* CvB = Cv + ((size_t)b << 14);

    for (int ch = 0; ch < 2; ++ch) {
        // stage 8 planes (8192 floats) via float4, scatter into stride-33 layout
        const float4* src = (const float4*)(sb + (ch << 13));
        #pragma unroll
        for (int q0 = 0; q0 < 8; ++q0) {
            int q = t + (q0 << 8);
            float4 val = src[q];
            int lin = q << 2;
            int n = lin >> 10, rem = lin & 1023;
            int di = 34 + n * 1056 + (rem >> 5) * 33 + (rem & 31);
            lds[di] = val.x; lds[di + 1] = val.y; lds[di + 2] = val.z; lds[di + 3] = val.w;
        }
        __syncthreads();

        const float* bvc = BvB + (ch << 13);
        const float* cvc = CvB + (ch << 13);
        float* soc = sob + (ch << 13);
        #pragma unroll
        for (int i = 0; i < 4; ++i) {
            int p = t + (i << 8);
            #pragma unroll
            for (int n = 0; n < 8; ++n) {
                int si = base[i] + n * 1056;
                float s00 = lds[si], s01 = lds[si + 1];
                float s10 = lds[si + 33], s11 = lds[si + 34];
                float bil = s00 * w00[i] + s01 * w01[i] + s10 * w10[i] + s11 * w11[i];
                float abar = __expf(dl[i] * Ash[(ch << 3) + n]);
                float sn = abar * bil + du[i] * bvc[(n << 10) + p];
                soc[(n << 10) + p] = sn;
                yacc[i] += sn * cvc[(n << 10) + p];
            }
        }
        __syncthreads();
    }

    float Dd = Dp[d];
    float* yo = y_out + (((size_t)((b * 8 + v) * 64 + d)) << 10);
    #pragma unroll
    for (int i = 0; i < 4; ++i) {
        int p = t + (i << 8);
        yo[p] = yacc[i] + uu[i] * Dd;
    }
}

// ---------------------------------------------------------------------------
extern "C" void kernel_launch(void* const* d_in, const int* in_sizes, int n_in,
                              void* d_out, int out_size, void* d_ws, size_t ws_size,
                              hipStream_t stream)
{
    const float* u_t    = (const float*)d_in[0];
    const float* s_prev = (const float*)d_in[1];
    const float* gn_w   = (const float*)d_in[2];
    const float* gn_b   = (const float*)d_in[3];
    const float* wd     = (const float*)d_in[4];
    const float* bd     = (const float*)d_in[5];
    const float* wB     = (const float*)d_in[6];
    const float* wC     = (const float*)d_in[7];
    const float* logA   = (const float*)d_in[8];
    const float* Dp     = (const float*)d_in[9];
    const float* dtb    = (const float*)d_in[10];

    float* y_out = (float*)d_out;            // (4,8,64,32,32) = 2097152 floats
    float* s_out = y_out + 2097152;          // (4,8,64,16,32,32) = 33554432 floats

    float* up    = (float*)d_ws;             // padded u_norm: 4*64*1156 = 295936
    float* delta = up + 295936;              // 4*64*1024 = 262144
    float* Bv    = delta + 262144;           // 4*16*1024 = 65536
    float* Cv    = Bv + 65536;               // 65536     (total ~2.76 MB of ws)

    hipLaunchKernelGGL(gn_kernel, dim3(16), dim3(256), 0, stream, u_t, gn_w, gn_b, up);
    hipLaunchKernelGGL(conv_kernel, dim3(384), dim3(256), 0, stream,
                       up, wd, bd, wB, wC, dtb, delta, Bv, Cv);
    hipLaunchKernelGGL(fused_state_kernel, dim3(2048), dim3(256), 0, stream,
                       s_prev, u_t, delta, Bv, Cv, logA, Dp, y_out, s_out);
}

// Round 2
// 319.316 us; speedup vs baseline: 1.0850x; 1.0850x over previous
//
#include <hip/hip_runtime.h>
#include <cmath>

// Shapes: B=4, V=8, D=64, N=16, H=32, W=32, GROUPS=4
// rotation tables: a = radians(-45*v); c = cos(a), s = sin(a)
#define FSQ 0.70710678118654752440f
__constant__ float CTAB[8] = {1.f,  FSQ, 0.f, -FSQ, -1.f, -FSQ, 0.f, FSQ};
__constant__ float STAB[8] = {0.f, -FSQ, -1.f, -FSQ,  0.f,  FSQ, 1.f, FSQ};

// ---------------------------------------------------------------------------
// GroupNorm: 16 blocks = (b, group). Writes u_norm into zero-padded (34x34)
// planes in ws (border zeros == conv SAME padding).
// ---------------------------------------------------------------------------
__global__ __launch_bounds__(256) void gn_kernel(const float* __restrict__ u,
                                                 const float* __restrict__ gw,
                                                 const float* __restrict__ gb,
                                                 float* __restrict__ up)
{
    int blk = blockIdx.x;            // b*4 + g
    int b = blk >> 2, g = blk & 3;
    int t = threadIdx.x;
    const float* src = u + ((size_t)(b * 64 + g * 16) << 10);   // 16384 floats
    float sum = 0.f, sq = 0.f;
    #pragma unroll
    for (int r = 0; r < 64; ++r) {
        float v = src[t + (r << 8)];
        sum += v; sq += v * v;
    }
    __shared__ float red[256], red2[256];
    red[t] = sum; red2[t] = sq;
    __syncthreads();
    for (int ofs = 128; ofs > 0; ofs >>= 1) {
        if (t < ofs) { red[t] += red[t + ofs]; red2[t] += red2[t + ofs]; }
        __syncthreads();
    }
    float mu  = red[0] * (1.f / 16384.f);
    float var = red2[0] * (1.f / 16384.f) - mu * mu;
    float rs  = rsqrtf(var + 1e-5f);

    float* pb = up + (size_t)(b * 64 + g * 16) * 1156;
    // zero the 132 border cells of each of my 16 padded planes
    for (int k = t; k < 16 * 132; k += 256) {
        int pl = k / 132, c = k % 132;
        int idx;
        if (c < 34)       idx = c;                       // row 0
        else if (c < 68)  idx = 33 * 34 + (c - 34);      // row 33
        else if (c < 100) idx = (c - 68 + 1) * 34;       // col 0, rows 1..32
        else              idx = (c - 100 + 1) * 34 + 33; // col 33, rows 1..32
        pb[pl * 1156 + idx] = 0.f;
    }
    // normalized data cells
    for (int r = 0; r < 64; ++r) {
        int idx = t + (r << 8);
        int ch = idx >> 10, rem = idx & 1023;
        int y = rem >> 5, x = rem & 31;
        float val = (src[idx] - mu) * rs * gw[g * 16 + ch] + gb[g * 16 + ch];
        pb[ch * 1156 + (y + 1) * 34 + (x + 1)] = val;
    }
}

// ---------------------------------------------------------------------------
// 3x3 SAME convs, LDS-staged: 3072 blocks = (b, o, strip). Each block stages
// the 6-row x 34-col x 64-ci input strip (52 KB) into LDS once (one sync),
// then 256 threads = 128 pixels x 2 ci-halves accumulate from LDS
// (consecutive-lane addresses -> conflict-free), one 2-way reduce.
// ---------------------------------------------------------------------------
__global__ __launch_bounds__(256) void conv_kernel(const float* __restrict__ up,
                                                   const float* __restrict__ wd,
                                                   const float* __restrict__ bd,
                                                   const float* __restrict__ wB,
                                                   const float* __restrict__ wC,
                                                   const float* __restrict__ dtb,
                                                   float* __restrict__ delta,
                                                   float* __restrict__ Bv,
                                                   float* __restrict__ Cv)
{
    __shared__ float sin_[64 * 204];   // 64 ci x 6 rows x 34 cols = 52224 B
    __shared__ float red[256];
    int blk = blockIdx.x;              // b*768 + o*8 + strip
    int strip = blk & 7;
    int o = (blk >> 3) & 127; o = o % 96;   // (blk>>3) % 96 but keep cheap
    o = ((blk >> 3) - (blk / 768) * 96);
    int b = blk / 768;
    int h0 = strip * 4;                // output rows h0..h0+3; padded rows h0..h0+5
    int t = threadIdx.x;

    const float* plane = up + (size_t)b * 73984;   // 64*1156
    for (int idx = t; idx < 13056; idx += 256) {   // 13056 = 64*204 = 256*51
        int ci = idx / 204;
        int rem = idx - ci * 204;
        sin_[idx] = plane[ci * 1156 + h0 * 34 + rem];
    }
    __syncthreads();

    const float* wsel;
    if (o < 64)      wsel = wd + (size_t)o * 576;
    else if (o < 80) wsel = wB + (size_t)(o - 64) * 576;
    else             wsel = wC + (size_t)(o - 80) * 576;

    int half = t >> 7;                 // ci-half (wave-uniform)
    int px = t & 127;
    int r = px >> 5, c = px & 31;      // output row-in-strip, col
    const float* base = sin_ + r * 34 + c;

    float acc = 0.f;
    int ci0 = half * 32;
    for (int ci = ci0; ci < ci0 + 32; ++ci) {
        const float* pp = base + ci * 204;
        const float* wp = wsel + ci * 9;
        #pragma unroll
        for (int dy = 0; dy < 3; ++dy)
            #pragma unroll
            for (int dx = 0; dx < 3; ++dx)
                acc += pp[dy * 34 + dx] * wp[dy * 3 + dx];
    }
    red[t] = acc;
    __syncthreads();
    if (t < 128) {
        float a = red[t] + red[t + 128];
        int pidx = (h0 + r) * 32 + c;
        if (o < 64) {
            float x = a + bd[o] + dtb[0];
            float sp = (x > 20.f) ? x : log1pf(expf(x));
            sp = fminf(fmaxf(sp, 1e-4f), 5.f);
            delta[((size_t)(b * 64 + o) << 10) + pidx] = sp;
        } else if (o < 80) {
            Bv[((size_t)(b * 16 + o - 64) << 10) + pidx] = a;
        } else {
            Cv[((size_t)(b * 16 + o - 80) << 10) + pidx] = a;
        }
    }
}

// ---------------------------------------------------------------------------
// Main fused kernel: 4096 blocks = (b, v, d, n-chunk of 8). Stages 8 planes
// of s_prev into LDS with row stride 34 (bank delta = dx+2*dy mod 32, never 0
// for any of the 8 rotations) + zero guard border, ONE sync, then bilinear
// transport + state update; s_new streamed out coalesced; y n-partials via
// atomicAdd (y pre-zeroed by hipMemsetAsync).
// Plane layout: idx = n*1156 + (y+1)*34 + (x+1), y,x in -1..32.
// ---------------------------------------------------------------------------
__global__ __launch_bounds__(256) void fused_state_kernel(
    const float* __restrict__ s_prev, const float* __restrict__ u_t,
    const float* __restrict__ delta, const float* __restrict__ Bv,
    const float* __restrict__ Cv, const float* __restrict__ logA,
    const float* __restrict__ Dp, float* __restrict__ y_out,
    float* __restrict__ s_out)
{
    __shared__ float lds[8 * 1156];   // 36992 B
    __shared__ float Ash[8];
    int blk = blockIdx.x;
    int cchunk = blk & 1;
    int d = (blk >> 1) & 63, v = (blk >> 7) & 7, b = blk >> 10;
    int t = threadIdx.x;

    if (t < 8) Ash[t] = -__expf(logA[d * 16 + cchunk * 8 + t]);
    // zero guard cells (8 planes x 132)
    for (int k = t; k < 1056; k += 256) {
        int pl = k >> 7; int g = k & 127;          // careful: 132 > 128 -> do exact
        pl = k / 132; g = k - pl * 132;
        int idx;
        if (g < 34)       idx = g;                  // row 0
        else if (g < 68)  idx = 1122 + (g - 34);    // row 33
        else if (g < 100) idx = (g - 67) * 34;      // col 0, rows 1..32
        else              idx = (g - 99) * 34 + 33; // col 33, rows 1..32
        lds[pl * 1156 + idx] = 0.f;
    }

    size_t so = (((size_t)((b * 8 + v) * 64 + d)) << 14) + (cchunk << 13);
    const float4* src = (const float4*)(s_prev + so);
    #pragma unroll
    for (int k = 0; k < 8; ++k) {
        int q = t + (k << 8);
        float4 val = src[q];
        int lin = q << 2;
        int nn = lin >> 10, rem = lin & 1023;
        int di = nn * 1156 + ((rem >> 5) + 1) * 34 + (rem & 31) + 1;
        lds[di] = val.x; lds[di + 1] = val.y; lds[di + 2] = val.z; lds[di + 3] = val.w;
    }
    __syncthreads();

    const float cc = CTAB[v], ss = STAB[v];
    const float* dpl = delta + ((size_t)(b * 64 + d) << 10);
    const float* upl = u_t   + ((size_t)(b * 64 + d) << 10);
    const float* bvc = Bv + ((size_t)b << 14) + (cchunk << 13);
    const float* cvc = Cv + ((size_t)b << 14) + (cchunk << 13);
    float* soc = s_out + so;
    float* yo  = y_out + (((size_t)((b * 8 + v) * 64 + d)) << 10);
    float Dd = Dp[d];

    for (int i = 0; i < 4; ++i) {
        int p = t + (i << 8);
        int h = p >> 5, wpx = p & 31;
        float X = (wpx + 0.5f) * 0.0625f - 1.f;
        float Y = (h + 0.5f) * 0.0625f - 1.f;
        float gx = cc * X - ss * Y;
        float gy = ss * X + cc * Y;
        float ix = (gx + 1.f) * 16.f - 0.5f;
        float iy = (gy + 1.f) * 16.f - 0.5f;
        float fx0 = floorf(ix), fy0 = floorf(iy);
        float wx = ix - fx0, wy = iy - fy0;
        int x0 = (int)fx0, y0 = (int)fy0;
        float mx0 = (x0 >= 0 && x0 < 32) ? (1.f - wx) : 0.f;
        float mx1 = (x0 >= -1 && x0 < 31) ? wx : 0.f;
        float my0 = (y0 >= 0 && y0 < 32) ? (1.f - wy) : 0.f;
        float my1 = (y0 >= -1 && y0 < 31) ? wy : 0.f;
        float w00 = my0 * mx0, w01 = my0 * mx1;
        float w10 = my1 * mx0, w11 = my1 * mx1;
        int bx = min(max(x0, -1), 31), by = min(max(y0, -1), 31);
        int base = (by + 1) * 34 + (bx + 1);   // taps: +0,+1,+34,+35 (guard is zeroed)

        float dd = dpl[p], uv = upl[p];
        float du = dd * uv;
        float yacc = 0.f;
        #pragma unroll
        for (int nn = 0; nn < 8; ++nn) {
            int si = base + nn * 1156;
            float s00 = lds[si], s01 = lds[si + 1];
            float s10 = lds[si + 34], s11 = lds[si + 35];
            float bil = s00 * w00 + s01 * w01 + s10 * w10 + s11 * w11;
            float abar = __expf(dd * Ash[nn]);
            float bvv = bvc[(nn << 10) + p];
            float sn = abar * bil + du * bvv;
            soc[(nn << 10) + p] = sn;
            yacc += sn * cvc[(nn << 10) + p];
        }
        float val = yacc + (cchunk == 0 ? uv * Dd : 0.f);
        atomicAdd(yo + p, val);
    }
}

// ---------------------------------------------------------------------------
extern "C" void kernel_launch(void* const* d_in, const int* in_sizes, int n_in,
                              void* d_out, int out_size, void* d_ws, size_t ws_size,
                              hipStream_t stream)
{
    const float* u_t    = (const float*)d_in[0];
    const float* s_prev = (const float*)d_in[1];
    const float* gn_w   = (const float*)d_in[2];
    const float* gn_b   = (const float*)d_in[3];
    const float* wd     = (const float*)d_in[4];
    const float* bd     = (const float*)d_in[5];
    const float* wB     = (const float*)d_in[6];
    const float* wC     = (const float*)d_in[7];
    const float* logA   = (const float*)d_in[8];
    const float* Dp     = (const float*)d_in[9];
    const float* dtb    = (const float*)d_in[10];

    float* y_out = (float*)d_out;            // (4,8,64,32,32) = 2097152 floats
    float* s_out = y_out + 2097152;          // (4,8,64,16,32,32) = 33554432 floats

    float* up    = (float*)d_ws;             // padded u_norm: 4*64*1156 = 295936
    float* delta = up + 295936;              // 4*64*1024 = 262144
    float* Bv    = delta + 262144;           // 4*16*1024 = 65536
    float* Cv    = Bv + 65536;               // 65536

    // y is accumulated via atomicAdd from the two n-chunk blocks -> zero first
    hipMemsetAsync(y_out, 0, (size_t)2097152 * sizeof(float), stream);

    hipLaunchKernelGGL(gn_kernel, dim3(16), dim3(256), 0, stream, u_t, gn_w, gn_b, up);
    hipLaunchKernelGGL(conv_kernel, dim3(3072), dim3(256), 0, stream,
                       up, wd, bd, wB, wC, dtb, delta, Bv, Cv);
    hipLaunchKernelGGL(fused_state_kernel, dim3(4096), dim3(256), 0, stream,
                       s_prev, u_t, delta, Bv, Cv, logA, Dp, y_out, s_out);
}